// Round 10
// baseline (389.172 us; speedup 1.0000x reference)
//
#include <hip/hip_runtime.h>
#include <hip/hip_fp16.h>

// N=1e6 nodes, E=32e6 edges.
// out[i] = (sum_{e: dst=i} h2[src_e]) / max(deg_in(i),1) * Wsage
// h2[v] = sum_j W2[j]*relu(W1[j]*x[v]+b1[j]) + b2
//
// R9 (on R8): aggregate was latency-bound on the dependent
// ent->src->gather chain (~1 gather in flight per lane). Now each block:
//   1) prefix-scans its 1024 run lengths (once),
//   2) stages each 8192-entry chunk of its bin compacted into LDS,
//   3) processes 16 entries/lane: ds_read x16 -> 16 INDEPENDENT global
//      gathers in flight -> 16 ds_add_f64.
// Scatter stays R8 (pure int sort, no gather, ~65us).
//
// ws layout: entries uint[NTILES*TILE]; index int[257*NTILES];
//            partial double[NSUB*NBINS*4096]; h2f16 ushort[n]; flag int.
// Fallback (ws too small or n >= 2^20): R1 packed f64-atomic path.

#define NBINS    256
#define BSHIFT   12
#define DMASK    4095
#define SRCBITS  20
#define NBLK     1024
#define STHREADS 512
#define EPT      16
#define TILE     (STHREADS * EPT)   // 8192
#define NSUB     4
#define RUNS     1024               // ntiles / NSUB
#define CH       8192               // staged entries per chunk
#define PACK_SCALE 1048576.0        // 2^20

// ---- dtype probe: int64 edge_index => every odd 32-bit word is 0 ----
__global__ void detect_dtype_kernel(const int* __restrict__ ei, int* __restrict__ flag) {
    if (threadIdx.x == 0 && blockIdx.x == 0) {
        int is64 = 1;
        for (int i = 1; i < 256; i += 2) {
            if (ei[i] != 0) { is64 = 0; break; }
        }
        *flag = is64;
    }
}

__global__ void node_kernel(const float* __restrict__ x,
                            const float* __restrict__ W1,
                            const float* __restrict__ b1,
                            const float* __restrict__ W2,
                            const float* __restrict__ b2,
                            unsigned short* __restrict__ h2f16,
                            int n) {
    int i = blockIdx.x * blockDim.x + threadIdx.x;
    if (i >= n) return;
    float xi = x[i];
    float acc = b2[0];
#pragma unroll
    for (int j = 0; j < 4; ++j) {
        float t = fmaxf(W1[j] * xi + b1[j], 0.0f);
        acc += W2[j] * t;
    }
    h2f16[i] = __half_as_ushort(__float2half(acc));
}

// P1: one-pass tile-sorted scatter into block-private slots + bin-major index.
// Entry = (dlow << 20) | src. No value gather here.
__global__ void __launch_bounds__(STHREADS)
scatter_tile_kernel(const int* __restrict__ ei,
                    unsigned int* __restrict__ entries,
                    int* __restrict__ index,   // [257][ntiles]
                    const int* __restrict__ flag,
                    long long E, long long chunk, int tpb, int ntiles) {
    __shared__ unsigned int ents[TILE];
    __shared__ int hist[NBINS];
    __shared__ int toff[NBINS];
    __shared__ int s_total;

    const int t = threadIdx.x;
    long long start = (long long)blockIdx.x * chunk;
    long long end   = start + chunk; if (end > E) end = E;
    const int is64 = *flag;
    const long long* e64 = (const long long*)ei;

    int ti = 0;
    for (long long tbase = start; tbase < end; tbase += TILE, ++ti) {
        for (int i = t; i < NBINS; i += STHREADS) hist[i] = 0;
        __syncthreads();

        // ---- phase 1: load all src/dst (independent loads in flight) ----
        int sk[EPT], dk[EPT];
        if (is64) {
#pragma unroll
            for (int k = 0; k < EPT; ++k) {
                long long e = tbase + (long long)k * STHREADS + t;
                if (e < end) {
                    sk[k] = (int)__builtin_nontemporal_load(&e64[e]);
                    dk[k] = (int)__builtin_nontemporal_load(&e64[E + e]);
                } else { sk[k] = 0; dk[k] = -1; }
            }
        } else {
#pragma unroll
            for (int k = 0; k < EPT; ++k) {
                long long e = tbase + (long long)k * STHREADS + t;
                if (e < end) {
                    sk[k] = __builtin_nontemporal_load(&ei[e]);
                    dk[k] = __builtin_nontemporal_load(&ei[E + e]);
                } else { sk[k] = 0; dk[k] = -1; }
            }
        }

        // ---- phase 2: rank within (tile, bin) ----
        int rk[EPT];
#pragma unroll
        for (int k = 0; k < EPT; ++k)
            if (dk[k] >= 0) rk[k] = atomicAdd(&hist[dk[k] >> BSHIFT], 1);
        __syncthreads();

        // ---- exclusive scan over 256 bins: wave 0 only, shfl scan ----
        if (t < 64) {
            const int base = t * 4;
            int a0 = hist[base], a1 = hist[base + 1],
                a2 = hist[base + 2], a3 = hist[base + 3];
            int s  = a0 + a1 + a2 + a3;
            int sc = s;
#pragma unroll
            for (int off = 1; off < 64; off <<= 1) {
                int up = __shfl_up(sc, off, 64);
                if (t >= off) sc += up;
            }
            int excl = sc - s;
            toff[base]     = excl;
            toff[base + 1] = excl + a0;
            toff[base + 2] = excl + a0 + a1;
            toff[base + 3] = excl + a0 + a1 + a2;
            if (t == 63) s_total = sc;
        }
        __syncthreads();

        // ---- phase 3: place bin-sorted in LDS ----
#pragma unroll
        for (int k = 0; k < EPT; ++k) {
            if (dk[k] >= 0) {
                int slot = toff[dk[k] >> BSHIFT] + rk[k];
                ents[slot] = ((unsigned int)(dk[k] & DMASK) << SRCBITS)
                           | (unsigned int)sk[k];
            }
        }
        __syncthreads();

        // ---- phase 4: vectorized coalesced copy-out + index row ----
        const int tilecount = s_total;
        const int g = blockIdx.x * tpb + ti;
        unsigned int* gout = entries + (long long)g * TILE;
        const int tc4 = (tilecount + 3) & ~3;
        for (int j = t * 4; j < tc4; j += STHREADS * 4) {
            uint4 val = *(const uint4*)&ents[j];     // ds_read_b128
            *(uint4*)&gout[j] = val;                 // dwordx4 store
        }
        if (t < NBINS)
            __builtin_nontemporal_store(toff[t], &index[(long long)t * ntiles + g]);
        else if (t == NBINS)
            __builtin_nontemporal_store(tilecount, &index[(long long)NBINS * ntiles + g]);
        __syncthreads();
    }
}

// P2: per-(bin,sub) aggregation with LDS run-staging for gather ILP.
// grid = NBINS*NSUB, 512 threads.
__global__ void __launch_bounds__(512)
aggregate_kernel(const unsigned int* __restrict__ entries,
                 const int* __restrict__ index,
                 const unsigned short* __restrict__ h2f16,
                 double* __restrict__ partial,   // [NSUB*NBINS][4096]
                 int ntiles) {
    __shared__ double       acc[4096];     // 32 KB
    __shared__ unsigned int stage[CH];     // 32 KB
    __shared__ int          pref[RUNS + 1];// 4.1 KB
    __shared__ int          sQ[RUNS];      // 4 KB: rowS per run
    __shared__ int          tsum[512];     // 2 KB

    const int b     = blockIdx.x >> 2;
    const int sub   = blockIdx.x & 3;
    const int t     = threadIdx.x;
    const int gbase = sub * RUNS;

    for (int i = t; i < 4096; i += 512) acc[i] = 0.0;

    // ---- run descriptors + prefix scan of lengths (once) ----
    const int* __restrict__ rowS = index + (long long)b * ntiles;
    const int* __restrict__ rowE = index + (long long)(b + 1) * ntiles;
    int r0 = 2 * t, r1 = 2 * t + 1;
    int s0 = rowS[gbase + r0], e0 = rowE[gbase + r0];
    int s1 = rowS[gbase + r1], e1 = rowE[gbase + r1];
    int l0 = e0 - s0, l1 = e1 - s1;
    sQ[r0] = s0; sQ[r1] = s1;
    tsum[t] = l0 + l1;
    __syncthreads();
    for (int off = 1; off < 512; off <<= 1) {
        int v = (t >= off) ? tsum[t - off] : 0;
        __syncthreads();
        tsum[t] += v;
        __syncthreads();
    }
    int excl = tsum[t] - (l0 + l1);
    pref[r0] = excl;
    pref[r1] = excl + l0;
    if (t == 511) pref[RUNS] = tsum[511];
    __syncthreads();

    const int T   = pref[RUNS];
    const int grp = t >> 5;      // 16 groups of 32 lanes
    const int hl  = t & 31;

    for (int c0 = 0; c0 < T; c0 += CH) {
        const int c1 = (c0 + CH < T) ? c0 + CH : T;

        // ---- stage: compact this chunk's runs into LDS ----
        for (int r = grp; r < RUNS; r += 16) {
            int off = pref[r];
            int len = pref[r + 1] - off;
            if (off + len <= c0 || off >= c1) continue;
            const unsigned int* run = entries + (long long)(gbase + r) * TILE + sQ[r];
            for (int i = hl; i < len; i += 32) {
                int pos = off + i;
                if (pos >= c0 && pos < c1)
                    stage[pos - c0] = __builtin_nontemporal_load(&run[i]);
            }
        }
        __syncthreads();

        // ---- process: 16 entries/lane, gathers fully in flight ----
        const int nthis = c1 - c0;
        unsigned int ev[16];
        unsigned short hv[16];
#pragma unroll
        for (int k = 0; k < 16; ++k) {
            int j = t + k * 512;
            ev[k] = (j < nthis) ? stage[j] : 0u;
        }
#pragma unroll
        for (int k = 0; k < 16; ++k)
            hv[k] = h2f16[ev[k] & ((1u << SRCBITS) - 1)];   // independent gathers
#pragma unroll
        for (int k = 0; k < 16; ++k) {
            int j = t + k * 512;
            if (j < nthis)
                atomicAdd(&acc[ev[k] >> SRCBITS],
                          (double)__half2float(__ushort_as_half(hv[k])) + PACK_SCALE);
        }
        __syncthreads();
    }

    double* p = partial + (long long)blockIdx.x * 4096;
    for (int i = t; i < 4096; i += 512)
        __builtin_nontemporal_store(acc[i], &p[i]);
}

// P3: finalize — merge NSUB partials per node, decode, write out.
__global__ void finalize_kernel(const double* __restrict__ partial,
                                const float* __restrict__ Wsage,
                                float* __restrict__ out,
                                int n) {
    int i = blockIdx.x * blockDim.x + threadIdx.x;
    if (i >= n) return;
    int b    = i >> BSHIFT;
    int dlow = i & DMASK;
    const double* p = partial + (long long)(b * NSUB) * 4096 + dlow;
    double v = p[0] + p[4096] + p[2 * 4096] + p[3 * 4096];
    double cnt = nearbyint(v * (1.0 / PACK_SCALE));
    double agg = v - cnt * PACK_SCALE;
    out[i] = (float)(agg / fmax(cnt, 1.0)) * Wsage[0];
}

// ---------------- fallback path (R1 packed-atomic) ----------------

__global__ void node_f32_kernel(const float* __restrict__ x,
                                const float* __restrict__ W1,
                                const float* __restrict__ b1,
                                const float* __restrict__ W2,
                                const float* __restrict__ b2,
                                float* __restrict__ h2,
                                int n) {
    int i = blockIdx.x * blockDim.x + threadIdx.x;
    if (i >= n) return;
    float xi = x[i];
    float acc = b2[0];
#pragma unroll
    for (int j = 0; j < 4; ++j) {
        float t = fmaxf(W1[j] * xi + b1[j], 0.0f);
        acc += W2[j] * t;
    }
    h2[i] = acc;
}

__global__ void zero_packed_kernel(double* __restrict__ packed, int n) {
    int i = blockIdx.x * blockDim.x + threadIdx.x;
    if (i < n) packed[i] = 0.0;
}

__global__ void edge_atomic_kernel(const int* __restrict__ ei,
                                   const float* __restrict__ h2,
                                   double* __restrict__ packed,
                                   const int* __restrict__ flag,
                                   long long E) {
    long long i      = (long long)blockIdx.x * blockDim.x + threadIdx.x;
    long long stride = (long long)gridDim.x * blockDim.x;
    const int is64 = *flag;
    if (is64) {
        const long long* e64 = (const long long*)ei;
        for (long long e = i; e < E; e += stride) {
            int s = (int)e64[e];
            int d = (int)e64[E + e];
            atomicAdd(&packed[d], (double)h2[s] + PACK_SCALE);
        }
    } else {
        for (long long e = i; e < E; e += stride) {
            int s = ei[e];
            int d = ei[E + e];
            atomicAdd(&packed[d], (double)h2[s] + PACK_SCALE);
        }
    }
}

__global__ void out_packed_kernel(const double* __restrict__ packed,
                                  const float* __restrict__ Wsage,
                                  float* __restrict__ out,
                                  int n) {
    int i = blockIdx.x * blockDim.x + threadIdx.x;
    if (i >= n) return;
    double v   = packed[i];
    double cnt = nearbyint(v * (1.0 / PACK_SCALE));
    double agg = v - cnt * PACK_SCALE;
    out[i] = (float)(agg / fmax(cnt, 1.0)) * Wsage[0];
}

extern "C" void kernel_launch(void* const* d_in, const int* in_sizes, int n_in,
                              void* d_out, int out_size, void* d_ws, size_t ws_size,
                              hipStream_t stream) {
    const float* x     = (const float*)d_in[0];
    const int*   ei    = (const int*)d_in[1];
    const float* W1    = (const float*)d_in[2];
    const float* b1    = (const float*)d_in[3];
    const float* W2    = (const float*)d_in[4];
    const float* b2    = (const float*)d_in[5];
    const float* Wsage = (const float*)d_in[6];

    const int       n = in_sizes[0];                 // 1,000,000
    const long long E = (long long)in_sizes[1] / 2;  // 32,000,000

    const long long chunk  = (E + NBLK - 1) / NBLK;            // 31250
    const int       tpb    = (int)((chunk + TILE - 1) / TILE); // 4
    const int       ntiles = NBLK * tpb;                       // 4096

    // ws layout
    const size_t entries_b = (size_t)ntiles * TILE * 4;
    const size_t index_b   = (size_t)(NBINS + 1) * ntiles * 4;
    const size_t partial_b = (size_t)NSUB * NBINS * 4096 * 8;
    const size_t h2_b      = (size_t)n * 2;
    const size_t need      = entries_b + index_b + partial_b + h2_b + 64;

    if (ws_size >= need && n <= (1 << SRCBITS) && ntiles == NSUB * RUNS) {
        unsigned int*   entries = (unsigned int*)d_ws;
        int*            index   = (int*)((char*)d_ws + entries_b);
        double*         partial = (double*)((char*)d_ws + entries_b + index_b);
        unsigned short* h2f16   = (unsigned short*)((char*)d_ws + entries_b + index_b + partial_b);
        int*            flag    = (int*)((char*)d_ws + entries_b + index_b + partial_b + h2_b);

        detect_dtype_kernel<<<1, 64, 0, stream>>>(ei, flag);
        {
            int threads = 256;
            int blocks  = (n + threads - 1) / threads;
            node_kernel<<<blocks, threads, 0, stream>>>(x, W1, b1, W2, b2, h2f16, n);
        }
        scatter_tile_kernel<<<NBLK, STHREADS, 0, stream>>>(ei, entries, index,
                                                           flag, E, chunk, tpb, ntiles);
        aggregate_kernel<<<NBINS * NSUB, 512, 0, stream>>>(entries, index, h2f16,
                                                           partial, ntiles);
        {
            int threads = 256;
            int blocks  = (n + threads - 1) / threads;
            finalize_kernel<<<blocks, threads, 0, stream>>>(partial, Wsage,
                                                            (float*)d_out, n);
        }
    } else {
        // fallback: R1 packed-atomic path
        double* packed = (double*)d_ws;
        float*  h2     = (float*)d_out;
        int*    flag   = (int*)(packed + n);

        detect_dtype_kernel<<<1, 64, 0, stream>>>(ei, flag);
        {
            int threads = 256;
            int blocks  = (n + threads - 1) / threads;
            node_f32_kernel<<<blocks, threads, 0, stream>>>(x, W1, b1, W2, b2, h2, n);
            zero_packed_kernel<<<blocks, threads, 0, stream>>>(packed, n);
        }
        edge_atomic_kernel<<<4096, 256, 0, stream>>>(ei, h2, packed, flag, E);
        {
            int threads = 256;
            int blocks  = (n + threads - 1) / threads;
            out_packed_kernel<<<blocks, threads, 0, stream>>>(packed, Wsage,
                                                              (float*)d_out, n);
        }
    }
}

// Round 11
// 340.195 us; speedup vs baseline: 1.1440x; 1.1440x over previous
//
#include <hip/hip_runtime.h>
#include <hip/hip_fp16.h>

// N=1e6 nodes, E=32e6 edges.
// out[i] = (sum_{e: dst=i} h2[src_e]) / max(deg_in(i),1) * Wsage
// h2[v] = sum_j W2[j]*relu(W1[j]*x[v]+b1[j]) + b2
//
// R10 (on R8): R9's staging regressed (38% occ, per-chunk descriptor scan).
// Back to R8's direct aggregate, but each 32-lane group now walks FOUR
// consecutive runs simultaneously (phase-split static arrays): 4 descriptor
// loads (coalesced), 4 entry loads in flight, 4 independent gathers in
// flight, 4 ds_add_f64. Runs avg 31<32 => inner while ~1 iteration.
// Scatter stays R8 (pure int sort, no gather, ~65us).
//
// ws layout: entries uint[NTILES*TILE]; index int[257*NTILES];
//            partial double[NSUB*NBINS*4096]; h2f16 ushort[n]; flag int.
// Fallback (ws too small or n >= 2^20): R1 packed f64-atomic path.

#define NBINS    256
#define BSHIFT   12
#define DMASK    4095
#define SRCBITS  20
#define SRCMASK  ((1u << SRCBITS) - 1)
#define NBLK     1024
#define STHREADS 512
#define EPT      16
#define TILE     (STHREADS * EPT)   // 8192
#define NSUB     4
#define PACK_SCALE 1048576.0        // 2^20

// ---- dtype probe: int64 edge_index => every odd 32-bit word is 0 ----
__global__ void detect_dtype_kernel(const int* __restrict__ ei, int* __restrict__ flag) {
    if (threadIdx.x == 0 && blockIdx.x == 0) {
        int is64 = 1;
        for (int i = 1; i < 256; i += 2) {
            if (ei[i] != 0) { is64 = 0; break; }
        }
        *flag = is64;
    }
}

__global__ void node_kernel(const float* __restrict__ x,
                            const float* __restrict__ W1,
                            const float* __restrict__ b1,
                            const float* __restrict__ W2,
                            const float* __restrict__ b2,
                            unsigned short* __restrict__ h2f16,
                            int n) {
    int i = blockIdx.x * blockDim.x + threadIdx.x;
    if (i >= n) return;
    float xi = x[i];
    float acc = b2[0];
#pragma unroll
    for (int j = 0; j < 4; ++j) {
        float t = fmaxf(W1[j] * xi + b1[j], 0.0f);
        acc += W2[j] * t;
    }
    h2f16[i] = __half_as_ushort(__float2half(acc));
}

// P1: one-pass tile-sorted scatter into block-private slots + bin-major index.
// Entry = (dlow << 20) | src. No value gather here.
__global__ void __launch_bounds__(STHREADS)
scatter_tile_kernel(const int* __restrict__ ei,
                    unsigned int* __restrict__ entries,
                    int* __restrict__ index,   // [257][ntiles]
                    const int* __restrict__ flag,
                    long long E, long long chunk, int tpb, int ntiles) {
    __shared__ unsigned int ents[TILE];
    __shared__ int hist[NBINS];
    __shared__ int toff[NBINS];
    __shared__ int s_total;

    const int t = threadIdx.x;
    long long start = (long long)blockIdx.x * chunk;
    long long end   = start + chunk; if (end > E) end = E;
    const int is64 = *flag;
    const long long* e64 = (const long long*)ei;

    int ti = 0;
    for (long long tbase = start; tbase < end; tbase += TILE, ++ti) {
        for (int i = t; i < NBINS; i += STHREADS) hist[i] = 0;
        __syncthreads();

        // ---- phase 1: load all src/dst (independent loads in flight) ----
        int sk[EPT], dk[EPT];
        if (is64) {
#pragma unroll
            for (int k = 0; k < EPT; ++k) {
                long long e = tbase + (long long)k * STHREADS + t;
                if (e < end) {
                    sk[k] = (int)__builtin_nontemporal_load(&e64[e]);
                    dk[k] = (int)__builtin_nontemporal_load(&e64[E + e]);
                } else { sk[k] = 0; dk[k] = -1; }
            }
        } else {
#pragma unroll
            for (int k = 0; k < EPT; ++k) {
                long long e = tbase + (long long)k * STHREADS + t;
                if (e < end) {
                    sk[k] = __builtin_nontemporal_load(&ei[e]);
                    dk[k] = __builtin_nontemporal_load(&ei[E + e]);
                } else { sk[k] = 0; dk[k] = -1; }
            }
        }

        // ---- phase 2: rank within (tile, bin) ----
        int rk[EPT];
#pragma unroll
        for (int k = 0; k < EPT; ++k)
            if (dk[k] >= 0) rk[k] = atomicAdd(&hist[dk[k] >> BSHIFT], 1);
        __syncthreads();

        // ---- exclusive scan over 256 bins: wave 0 only, shfl scan ----
        if (t < 64) {
            const int base = t * 4;
            int a0 = hist[base], a1 = hist[base + 1],
                a2 = hist[base + 2], a3 = hist[base + 3];
            int s  = a0 + a1 + a2 + a3;
            int sc = s;
#pragma unroll
            for (int off = 1; off < 64; off <<= 1) {
                int up = __shfl_up(sc, off, 64);
                if (t >= off) sc += up;
            }
            int excl = sc - s;
            toff[base]     = excl;
            toff[base + 1] = excl + a0;
            toff[base + 2] = excl + a0 + a1;
            toff[base + 3] = excl + a0 + a1 + a2;
            if (t == 63) s_total = sc;
        }
        __syncthreads();

        // ---- phase 3: place bin-sorted in LDS ----
#pragma unroll
        for (int k = 0; k < EPT; ++k) {
            if (dk[k] >= 0) {
                int slot = toff[dk[k] >> BSHIFT] + rk[k];
                ents[slot] = ((unsigned int)(dk[k] & DMASK) << SRCBITS)
                           | (unsigned int)sk[k];
            }
        }
        __syncthreads();

        // ---- phase 4: vectorized coalesced copy-out + index row ----
        const int tilecount = s_total;
        const int g = blockIdx.x * tpb + ti;
        unsigned int* gout = entries + (long long)g * TILE;
        const int tc4 = (tilecount + 3) & ~3;
        for (int j = t * 4; j < tc4; j += STHREADS * 4) {
            uint4 val = *(const uint4*)&ents[j];     // ds_read_b128
            *(uint4*)&gout[j] = val;                 // dwordx4 store
        }
        if (t < NBINS)
            __builtin_nontemporal_store(toff[t], &index[(long long)t * ntiles + g]);
        else if (t == NBINS)
            __builtin_nontemporal_store(tilecount, &index[(long long)NBINS * ntiles + g]);
        __syncthreads();
    }
}

// P2: per-(bin,sub) aggregation; each 32-lane group walks 4 runs at once.
// grid = NBINS*NSUB, 512 threads.
__global__ void __launch_bounds__(512)
aggregate_kernel(const unsigned int* __restrict__ entries,
                 const int* __restrict__ index,
                 const unsigned short* __restrict__ h2f16,
                 double* __restrict__ partial,   // [NSUB*NBINS][4096]
                 int ntiles) {
    __shared__ double acc[4096];
    const int b   = blockIdx.x >> 2;
    const int sub = blockIdx.x & 3;
    const int t   = threadIdx.x;
    for (int i = t; i < 4096; i += 512) acc[i] = 0.0;
    __syncthreads();

    const int quarter = ntiles >> 2;     // runs per sub-block
    const int gbase   = sub * quarter;
    const int grp = t >> 5;              // 16 groups of 32 lanes
    const int hl  = t & 31;
    const int* __restrict__ rowS = index + (long long)b * ntiles;
    const int* __restrict__ rowE = index + (long long)(b + 1) * ntiles;

    for (int g = gbase + grp * 4; g < gbase + quarter; g += 64) {
        // 4 run descriptors (consecutive -> coalesced within group)
        int s[4], e[4];
#pragma unroll
        for (int q = 0; q < 4; ++q) { s[q] = rowS[g + q]; e[q] = rowE[g + q]; }

        int idx[4];
#pragma unroll
        for (int q = 0; q < 4; ++q) idx[q] = s[q] + hl;

        while (idx[0] < e[0] || idx[1] < e[1] || idx[2] < e[2] || idx[3] < e[3]) {
            unsigned int ev[4];
            bool act[4];
            // phase A: 4 independent entry loads in flight
#pragma unroll
            for (int q = 0; q < 4; ++q) {
                act[q] = idx[q] < e[q];
                const unsigned int* run = entries + (long long)(g + q) * TILE;
                ev[q] = act[q] ? __builtin_nontemporal_load(&run[idx[q]]) : 0u;
            }
            // phase B: 4 independent gathers in flight
            unsigned short hv[4];
#pragma unroll
            for (int q = 0; q < 4; ++q) hv[q] = h2f16[ev[q] & SRCMASK];
            // phase C: 4 ds_add_f64
#pragma unroll
            for (int q = 0; q < 4; ++q) {
                if (act[q])
                    atomicAdd(&acc[ev[q] >> SRCBITS],
                              (double)__half2float(__ushort_as_half(hv[q])) + PACK_SCALE);
                idx[q] += 32;
            }
        }
    }
    __syncthreads();

    double* p = partial + (long long)blockIdx.x * 4096;
    for (int i = t; i < 4096; i += 512)
        __builtin_nontemporal_store(acc[i], &p[i]);
}

// P3: finalize — merge NSUB partials per node, decode, write out.
__global__ void finalize_kernel(const double* __restrict__ partial,
                                const float* __restrict__ Wsage,
                                float* __restrict__ out,
                                int n) {
    int i = blockIdx.x * blockDim.x + threadIdx.x;
    if (i >= n) return;
    int b    = i >> BSHIFT;
    int dlow = i & DMASK;
    const double* p = partial + (long long)(b * NSUB) * 4096 + dlow;
    double v = p[0] + p[4096] + p[2 * 4096] + p[3 * 4096];
    double cnt = nearbyint(v * (1.0 / PACK_SCALE));
    double agg = v - cnt * PACK_SCALE;
    out[i] = (float)(agg / fmax(cnt, 1.0)) * Wsage[0];
}

// ---------------- fallback path (R1 packed-atomic) ----------------

__global__ void node_f32_kernel(const float* __restrict__ x,
                                const float* __restrict__ W1,
                                const float* __restrict__ b1,
                                const float* __restrict__ W2,
                                const float* __restrict__ b2,
                                float* __restrict__ h2,
                                int n) {
    int i = blockIdx.x * blockDim.x + threadIdx.x;
    if (i >= n) return;
    float xi = x[i];
    float acc = b2[0];
#pragma unroll
    for (int j = 0; j < 4; ++j) {
        float t = fmaxf(W1[j] * xi + b1[j], 0.0f);
        acc += W2[j] * t;
    }
    h2[i] = acc;
}

__global__ void zero_packed_kernel(double* __restrict__ packed, int n) {
    int i = blockIdx.x * blockDim.x + threadIdx.x;
    if (i < n) packed[i] = 0.0;
}

__global__ void edge_atomic_kernel(const int* __restrict__ ei,
                                   const float* __restrict__ h2,
                                   double* __restrict__ packed,
                                   const int* __restrict__ flag,
                                   long long E) {
    long long i      = (long long)blockIdx.x * blockDim.x + threadIdx.x;
    long long stride = (long long)gridDim.x * blockDim.x;
    const int is64 = *flag;
    if (is64) {
        const long long* e64 = (const long long*)ei;
        for (long long e = i; e < E; e += stride) {
            int s = (int)e64[e];
            int d = (int)e64[E + e];
            atomicAdd(&packed[d], (double)h2[s] + PACK_SCALE);
        }
    } else {
        for (long long e = i; e < E; e += stride) {
            int s = ei[e];
            int d = ei[E + e];
            atomicAdd(&packed[d], (double)h2[s] + PACK_SCALE);
        }
    }
}

__global__ void out_packed_kernel(const double* __restrict__ packed,
                                  const float* __restrict__ Wsage,
                                  float* __restrict__ out,
                                  int n) {
    int i = blockIdx.x * blockDim.x + threadIdx.x;
    if (i >= n) return;
    double v   = packed[i];
    double cnt = nearbyint(v * (1.0 / PACK_SCALE));
    double agg = v - cnt * PACK_SCALE;
    out[i] = (float)(agg / fmax(cnt, 1.0)) * Wsage[0];
}

extern "C" void kernel_launch(void* const* d_in, const int* in_sizes, int n_in,
                              void* d_out, int out_size, void* d_ws, size_t ws_size,
                              hipStream_t stream) {
    const float* x     = (const float*)d_in[0];
    const int*   ei    = (const int*)d_in[1];
    const float* W1    = (const float*)d_in[2];
    const float* b1    = (const float*)d_in[3];
    const float* W2    = (const float*)d_in[4];
    const float* b2    = (const float*)d_in[5];
    const float* Wsage = (const float*)d_in[6];

    const int       n = in_sizes[0];                 // 1,000,000
    const long long E = (long long)in_sizes[1] / 2;  // 32,000,000

    const long long chunk  = (E + NBLK - 1) / NBLK;            // 31250
    const int       tpb    = (int)((chunk + TILE - 1) / TILE); // 4
    const int       ntiles = NBLK * tpb;                       // 4096

    // ws layout
    const size_t entries_b = (size_t)ntiles * TILE * 4;
    const size_t index_b   = (size_t)(NBINS + 1) * ntiles * 4;
    const size_t partial_b = (size_t)NSUB * NBINS * 4096 * 8;
    const size_t h2_b      = (size_t)n * 2;
    const size_t need      = entries_b + index_b + partial_b + h2_b + 64;

    if (ws_size >= need && n <= (1 << SRCBITS) && (ntiles & (4 * 64 - 1)) == 0) {
        unsigned int*   entries = (unsigned int*)d_ws;
        int*            index   = (int*)((char*)d_ws + entries_b);
        double*         partial = (double*)((char*)d_ws + entries_b + index_b);
        unsigned short* h2f16   = (unsigned short*)((char*)d_ws + entries_b + index_b + partial_b);
        int*            flag    = (int*)((char*)d_ws + entries_b + index_b + partial_b + h2_b);

        detect_dtype_kernel<<<1, 64, 0, stream>>>(ei, flag);
        {
            int threads = 256;
            int blocks  = (n + threads - 1) / threads;
            node_kernel<<<blocks, threads, 0, stream>>>(x, W1, b1, W2, b2, h2f16, n);
        }
        scatter_tile_kernel<<<NBLK, STHREADS, 0, stream>>>(ei, entries, index,
                                                           flag, E, chunk, tpb, ntiles);
        aggregate_kernel<<<NBINS * NSUB, 512, 0, stream>>>(entries, index, h2f16,
                                                           partial, ntiles);
        {
            int threads = 256;
            int blocks  = (n + threads - 1) / threads;
            finalize_kernel<<<blocks, threads, 0, stream>>>(partial, Wsage,
                                                            (float*)d_out, n);
        }
    } else {
        // fallback: R1 packed-atomic path
        double* packed = (double*)d_ws;
        float*  h2     = (float*)d_out;
        int*    flag   = (int*)(packed + n);

        detect_dtype_kernel<<<1, 64, 0, stream>>>(ei, flag);
        {
            int threads = 256;
            int blocks  = (n + threads - 1) / threads;
            node_f32_kernel<<<blocks, threads, 0, stream>>>(x, W1, b1, W2, b2, h2, n);
            zero_packed_kernel<<<blocks, threads, 0, stream>>>(packed, n);
        }
        edge_atomic_kernel<<<4096, 256, 0, stream>>>(ei, h2, packed, flag, E);
        {
            int threads = 256;
            int blocks  = (n + threads - 1) / threads;
            out_packed_kernel<<<blocks, threads, 0, stream>>>(packed, Wsage,
                                                              (float*)d_out, n);
        }
    }
}